// Round 11
// baseline (92.806 us; speedup 1.0000x reference)
//
#include <hip/hip_runtime.h>
#include <hip/hip_bf16.h>

typedef _Float16 half8 __attribute__((ext_vector_type(8)));
typedef _Float16 half4 __attribute__((ext_vector_type(4)));
typedef _Float16 half2v __attribute__((ext_vector_type(2)));
typedef float    f32x4 __attribute__((ext_vector_type(4)));

constexpr int Bb = 1024;
constexpr int TS = 512;   // 8 waves, 2 M-tiles per wave

// ---- workspace byte offsets ----
constexpr int W_MTH  = 65536;    // f16 [64][256]  Mt[d][s]
constexpr int W_WEKH = 98304;    // f16 [64][64]   WekT[k][d]
constexpr int W_WEQH = 106496;   // f16 [64][64]   WeqT[k][d]
constexpr int W_BEQ  = 114688;   // f32[64]
constexpr int W_CB   = 116992;   // f32[256]
constexpr int W_MS   = 118016;   // f32[64]
constexpr int W_C0   = 118272;   // f32[1]

#define MFMA16(A, B, C) __builtin_amdgcn_mfma_f32_16x16x32_f16((A), (B), (C), 0, 0, 0)

__device__ __forceinline__ half8 cvt8(const float* p) {
  float4 v0 = *(const float4*)p, v1 = *(const float4*)(p + 4);
  half8 h;
  h[0] = (_Float16)v0.x; h[1] = (_Float16)v0.y; h[2] = (_Float16)v0.z; h[3] = (_Float16)v0.w;
  h[4] = (_Float16)v1.x; h[5] = (_Float16)v1.y; h[6] = (_Float16)v1.z; h[7] = (_Float16)v1.w;
  return h;
}

// ONE fused pre kernel. Grid 33 x 256.
//  blocks 0..15 : Mt s-tile via Mt = W_emb @ (W_v @ W_d^T)   (two MFMA stages thru LDS)
//  blocks 16..23: WekT  (512 elems each)
//  blocks 24..31: WeqT
//  block  32    : cs,bev,beq -> vcs,cb -> ms,c0   (vcs = W_v@cs so ms needs no Wev)
__global__ __launch_bounds__(256) void pre_kernel(
    const float* __restrict__ W_emb, const float* __restrict__ b_emb,
    const float* __restrict__ W_k,   const float* __restrict__ W_q,
    const float* __restrict__ b_q,   const float* __restrict__ W_v,
    const float* __restrict__ b_v,   const float* __restrict__ W_d,
    const float* __restrict__ b_d,   char* __restrict__ wsb) {
  __shared__ __align__(16) char lds[16 * 264 * 2];   // P2T [16][264] f16 (padded) / vectors overlay
  const int blk = blockIdx.x, t = threadIdx.x;

  if (blk < 16) {
    // ---- Mt s-tile: s0..s0+16 ----
    const int w = t >> 6, l = t & 63, lhi = l >> 4, llo = l & 15;
    const int s0 = blk * 16;
    _Float16* P2T = (_Float16*)lds;          // [16][264]
    f32x4 zero4 = {0.f, 0.f, 0.f, 0.f};
    // stage A: P2[hp][s] = sum_h W_v[hp,h] * W_d[s,h]; wave w -> hp tiles w*64 + {0,16,32,48}
    {
      f32x4 cp[4];
#pragma unroll
      for (int mt = 0; mt < 4; ++mt) cp[mt] = zero4;
      for (int ks = 0; ks < 8; ++ks) {
        const int kd = ks * 32 + lhi * 8;
        half8 Bf = cvt8(W_d + (s0 + llo) * 256 + kd);
#pragma unroll
        for (int mt = 0; mt < 4; ++mt) {
          half8 Afr = cvt8(W_v + (w * 64 + mt * 16 + llo) * 256 + kd);
          cp[mt] = MFMA16(Afr, Bf, cp[mt]);
        }
      }
      // C: col s=llo, rows hp = base+lhi*4+r -> P2T[s][hp] (half4, 8B-aligned)
#pragma unroll
      for (int mt = 0; mt < 4; ++mt) {
        half4 hv;
#pragma unroll
        for (int r = 0; r < 4; ++r) hv[r] = (_Float16)cp[mt][r];
        *(half4*)(P2T + llo * 264 + w * 64 + mt * 16 + lhi * 4) = hv;
      }
    }
    __syncthreads();
    // stage B: Mt[d][s] = sum_hp W_emb[d,hp] * P2[hp][s]; wave w -> d tile w*16
    {
      f32x4 cm = zero4;
      for (int ks = 0; ks < 8; ++ks) {
        const int kd = ks * 32 + lhi * 8;
        half8 Afr = cvt8(W_emb + (w * 16 + llo) * 256 + kd);
        half8 Bf  = *(const half8*)(P2T + llo * 264 + kd);
        cm = MFMA16(Afr, Bf, cm);
      }
      _Float16* mth = (_Float16*)(wsb + W_MTH);
#pragma unroll
      for (int r = 0; r < 4; ++r)
        mth[(w * 16 + lhi * 4 + r) * 256 + s0 + llo] = (_Float16)cm[r];
    }
  } else if (blk < 32) {
    // ---- WekT / WeqT: elem e -> (d=e>>6, k=e&63); out[k*64+d] ----
    const bool isK = blk < 24;
    const float* Wx = isK ? W_k : W_q;
    _Float16* outp = (_Float16*)(wsb + (isK ? W_WEKH : W_WEQH));
    const int base = ((blk - (isK ? 16 : 24)) * 512);
#pragma unroll
    for (int j = 0; j < 2; ++j) {
      int e = base + j * 256 + t;
      int d = e >> 6, k = e & 63;
      const float* we = W_emb + d * 256;
      float a = 0.f;
#pragma unroll 4
      for (int h = 0; h < 256; ++h) a += we[h] * Wx[h * 64 + k];
      outp[k * 64 + d] = (_Float16)a;
    }
  } else {
    // ---- vectors ----
    float* cs_l  = (float*)lds;            // 256
    float* bev_l = cs_l + 256;             // 256
    float* beq_l = bev_l + 256;            // 64
    float* vcs_l = beq_l + 64;             // 256
    {
      float a = 0.f;
#pragma unroll 4
      for (int s = 0; s < 256; ++s) a += W_d[s * 256 + t];
      cs_l[t] = a;
      float b = b_v[t];
#pragma unroll 4
      for (int hp = 0; hp < 256; ++hp) b += b_emb[hp] * W_v[hp * 256 + t];
      bev_l[t] = b;
      if (t < 64) {
        float c = b_q[t];
#pragma unroll 4
        for (int h = 0; h < 256; ++h) c += b_emb[h] * W_q[h * 64 + t];
        beq_l[t] = c;
        ((float*)(wsb + W_BEQ))[t] = c;
      }
    }
    __syncthreads();
    {
      float v = 0.f, cbv = 0.f;
      const float* wvr = W_v + t * 256;
      const float* wdr = W_d + t * 256;
#pragma unroll 4
      for (int h = 0; h < 256; ++h) { v += wvr[h] * cs_l[h]; cbv += wdr[h] * bev_l[h]; }
      vcs_l[t] = v;
      ((float*)(wsb + W_CB))[t] = cbv;
    }
    __syncthreads();
    if (t < 64) {
      float m = 0.f;
      const float* wer = W_emb + t * 256;
#pragma unroll 4
      for (int hp = 0; hp < 256; ++hp) m += wer[hp] * vcs_l[hp];
      ((float*)(wsb + W_MS))[t] = m;
    }
    if (t == 0) {
      float cb2 = 0.f;
      for (int h = 0; h < 256; ++h) cb2 += cs_l[h] * bev_l[h];
      float bq = 0.f;
      for (int k = 0; k < 64; ++k) bq += beq_l[k];
      ((float*)(wsb + W_C0))[0] = b_d[0] + cb2 * bq;
    }
  }
}

// LDS byte-address helpers (G4 XOR swizzle)
__device__ __forceinline__ int adrR(int r, int c) {   // QT [64][256] f16 at 0, rows 512B
  return (((r << 9) + (c << 1)) ^ ((r & 7) << 4));
}
__device__ __forceinline__ int adrU(int k, int d) {   // U  [64][64]  f16 at 32768, rows 128B
  return 32768 + (((k << 7) + (d << 1)) ^ ((k & 7) << 4));
}

// One block per batch, 8 waves, wave w owns s-rows 32w..32w+31 (2 row-tiles).
// LDS: QT 32K | U 8K | scr floats at 40960.
// REG BUDGET: merged pass peak ~110 live (clg32+cq32+Af16+frags16+addr) -> needs the
// (512,4)=128 cap. (512,6) collapses the allocator -> wholesale spill (R8/R9 lesson).
__global__ __launch_bounds__(TS, 4) void main_kernel(const float* __restrict__ inp_g,
                                                     const char* __restrict__ wsb,
                                                     float* __restrict__ out) {
  __shared__ __align__(16) char smem[43136];
  float* scrf = (float*)(smem + 40960);

  const int b = blockIdx.x, t = threadIdx.x;
  const int l = t & 63, w = t >> 6;            // w = 0..7
  const int lhi = l >> 4, llo = l & 15;

  const float* inp = inp_g + (size_t)b * 16384;

  // ---- A-fragments of inp straight from global (used in merged pass AND Phase E) ----
  half8 Af[4];   // [tl*2+ks]
  {
    const int srA = w * 32 + llo;
#pragma unroll
    for (int tl = 0; tl < 2; ++tl)
#pragma unroll
      for (int ks = 0; ks < 2; ++ks)
        Af[tl * 2 + ks] = cvt8(inp + (srA + tl * 16) * 64 + ks * 32 + lhi * 8);
  }

  f32x4 zero4 = {0.f, 0.f, 0.f, 0.f};
  float acc = 0.f;
  half2v ep[2][4][2];   // packed exp(logits)

  // ---- merged pass: logits = inp@Wek AND Q = inp@Weq (32 indep MFMAs/ks) ----
  f32x4 clg[2][4], cq[2][4];
#pragma unroll
  for (int tl = 0; tl < 2; ++tl)
#pragma unroll
    for (int n = 0; n < 4; ++n) { clg[tl][n] = zero4; cq[tl][n] = zero4; }
  {
    const _Float16* wekh = (const _Float16*)(wsb + W_WEKH);
    const _Float16* weqh = (const _Float16*)(wsb + W_WEQH);
#pragma unroll
    for (int ks = 0; ks < 2; ++ks) {
      const int kd = ks * 32 + lhi * 8;
      half8 Bk[4], Bq[4];
#pragma unroll
      for (int n = 0; n < 4; ++n) {
        Bk[n] = *(const half8*)(wekh + (n * 16 + llo) * 64 + kd);
        Bq[n] = *(const half8*)(weqh + (n * 16 + llo) * 64 + kd);
      }
#pragma unroll
      for (int n = 0; n < 4; ++n) {
        clg[0][n] = MFMA16(Af[ks],     Bk[n], clg[0][n]);
        clg[1][n] = MFMA16(Af[2 + ks], Bk[n], clg[1][n]);
        cq[0][n]  = MFMA16(Af[ks],     Bq[n], cq[0][n]);
        cq[1][n]  = MFMA16(Af[2 + ks], Bq[n], cq[1][n]);
      }
    }
  }

  // ---- exp (no max: bias cancels, |logit| small) + colsum partials (kills clg) ----
#pragma unroll
  for (int n = 0; n < 4; ++n) {
    float sum = 0.f;
    float ev[2][4];
#pragma unroll
    for (int tl = 0; tl < 2; ++tl)
#pragma unroll
      for (int r = 0; r < 4; ++r) { ev[tl][r] = __expf(clg[tl][n][r]); sum += ev[tl][r]; }
#pragma unroll
    for (int tl = 0; tl < 2; ++tl) {
      half2v p0, p1;
      p0[0] = (_Float16)ev[tl][0]; p0[1] = (_Float16)ev[tl][1];
      p1[0] = (_Float16)ev[tl][2]; p1[1] = (_Float16)ev[tl][3];
      ep[tl][n][0] = p0; ep[tl][n][1] = p1;
    }
    sum += __shfl_xor(sum, 16);
    sum += __shfl_xor(sum, 32);
    if (lhi == 0) scrf[(n * 16 + llo) * 8 + w] = sum;
  }

  // ---- QT write (f16, LDS) + cb-term (kills cq) ----
  {
#pragma unroll
    for (int tl = 0; tl < 2; ++tl) {
      int sbase = w * 32 + tl * 16 + lhi * 4;
#pragma unroll
      for (int n = 0; n < 4; ++n) {
        half4 qh;
#pragma unroll
        for (int r = 0; r < 4; ++r) qh[r] = (_Float16)cq[tl][n][r];
        *(half4*)(smem + adrR(n * 16 + llo, sbase)) = qh;
      }
    }
    const float* cb = (const float*)(wsb + W_CB);
#pragma unroll
    for (int tl = 0; tl < 2; ++tl)
#pragma unroll
      for (int r = 0; r < 4; ++r) {
        float qs = (cq[tl][0][r] + cq[tl][1][r]) + (cq[tl][2][r] + cq[tl][3][r]);
        acc += cb[w * 32 + tl * 16 + lhi * 4 + r] * qs;
      }
  }

  // ---- Bm prefetch for Phase D (cq dead; ~70 live regs here, fits 128 budget) ----
  const int d0 = (w & 3) * 16;
  const int ka = (w >> 2) * 16, kb = ka + 32;
  half8 Bm[8];
  {
    const _Float16* mth = (const _Float16*)(wsb + W_MTH);
#pragma unroll
    for (int j = 0; j < 8; ++j)
      Bm[j] = *(const half8*)(mth + (d0 + llo) * 256 + j * 32 + lhi * 8);
  }
  __syncthreads();   // bar 1: QT + colsum partials visible

  // ---- Phase D: T = QT x Mt (K=256); U[k][d] = T + beq[k]*ms[d] -> LDS f16 ----
  {
    f32x4 cta = zero4, ctb = zero4;
#pragma unroll
    for (int ks = 0; ks < 8; ++ks) {
      const int kd = ks * 32 + lhi * 8;
      half8 Aqa = *(const half8*)(smem + adrR(ka + llo, kd));
      half8 Aqb = *(const half8*)(smem + adrR(kb + llo, kd));
      cta = MFMA16(Aqa, Bm[ks], cta);
      ctb = MFMA16(Aqb, Bm[ks], ctb);
    }
    const float* beq = (const float*)(wsb + W_BEQ);
    const float* msv = (const float*)(wsb + W_MS);
    float msd = msv[d0 + llo];
#pragma unroll
    for (int r = 0; r < 4; ++r) {
      float Uva = cta[r] + beq[ka + lhi * 4 + r] * msd;
      *(_Float16*)(smem + adrU(ka + lhi * 4 + r, d0 + llo)) = (_Float16)Uva;
      float Uvb = ctb[r] + beq[kb + lhi * 4 + r] * msd;
      *(_Float16*)(smem + adrU(kb + lhi * 4 + r, d0 + llo)) = (_Float16)Uvb;
    }
  }
  __syncthreads();   // bar 2: U visible

  // ---- Phase E: G = inp @ U^T (reuses Af); acc += sum e*cg / colsum ----
  {
    f32x4 cga[4], cgb[4];
#pragma unroll
    for (int n = 0; n < 4; ++n) { cga[n] = zero4; cgb[n] = zero4; }
#pragma unroll
    for (int ks = 0; ks < 2; ++ks) {
      const int kd = ks * 32 + lhi * 8;
      half8 Bu[4];
#pragma unroll
      for (int n = 0; n < 4; ++n) Bu[n] = *(const half8*)(smem + adrU(n * 16 + llo, kd));
#pragma unroll
      for (int n = 0; n < 4; ++n) {
        cga[n] = MFMA16(Af[ks],     Bu[n], cga[n]);
        cgb[n] = MFMA16(Af[2 + ks], Bu[n], cgb[n]);
      }
    }
#pragma unroll
    for (int n = 0; n < 4; ++n) {
      const float4* cp = (const float4*)(scrf + (n * 16 + llo) * 8);
      float4 c0v = cp[0], c1v = cp[1];
      float ss = ((c0v.x + c0v.y) + (c0v.z + c0v.w)) + ((c1v.x + c1v.y) + (c1v.z + c1v.w));
      float rs = __builtin_amdgcn_rcpf(ss);
      float dot = 0.f;
#pragma unroll
      for (int r = 0; r < 4; ++r) {
        float ea = (float)ep[0][n][r >> 1][r & 1];
        float eb = (float)ep[1][n][r >> 1][r & 1];
        dot += ea * cga[n][r] + eb * cgb[n][r];
      }
      acc += dot * rs;
    }
  }

  // ---- block reduction ----
#pragma unroll
  for (int off = 32; off; off >>= 1) acc += __shfl_down(acc, off);
  if (l == 0) scrf[512 + w] = acc;
  __syncthreads();   // bar 3
  if (t == 0) {
    float tot = ((const float*)(wsb + W_C0))[0];
#pragma unroll
    for (int g = 0; g < 8; ++g) tot += scrf[512 + g];
    out[b] = tot;
  }
}

extern "C" void kernel_launch(void* const* d_in, const int* in_sizes, int n_in,
                              void* d_out, int out_size, void* d_ws, size_t ws_size,
                              hipStream_t stream) {
  (void)in_sizes; (void)n_in; (void)out_size; (void)ws_size;
  const float* input_seq = (const float*)d_in[0];
  const float* W_emb = (const float*)d_in[1];
  const float* b_emb = (const float*)d_in[2];
  const float* W_k   = (const float*)d_in[3];
  const float* W_q   = (const float*)d_in[5];
  const float* b_q   = (const float*)d_in[6];
  const float* W_v   = (const float*)d_in[7];
  const float* b_v   = (const float*)d_in[8];
  const float* W_d   = (const float*)d_in[9];
  const float* b_d   = (const float*)d_in[10];
  char* wsb  = (char*)d_ws;
  float* out = (float*)d_out;

  pre_kernel<<<33, 256, 0, stream>>>(
      W_emb, b_emb, W_k, W_q, b_q, W_v, b_v, W_d, b_d, wsb);
  main_kernel<<<Bb, TS, 0, stream>>>(input_seq, wsb, out);
}

// Round 13
// 81.067 us; speedup vs baseline: 1.1448x; 1.1448x over previous
//
#include <hip/hip_runtime.h>
#include <hip/hip_bf16.h>

typedef _Float16 half8 __attribute__((ext_vector_type(8)));
typedef _Float16 half4 __attribute__((ext_vector_type(4)));
typedef _Float16 half2v __attribute__((ext_vector_type(2)));
typedef float    f32x4 __attribute__((ext_vector_type(4)));

constexpr int Bb = 1024;
constexpr int TS = 512;   // 8 waves; each block handles TWO batch elements

// ---- workspace byte offsets (R10 layout) ----
constexpr int W_WEV  = 0;        // f32 [64][256]  Wev[d][h]   (pre1 -> pre2 only)
constexpr int W_MTH  = 65536;    // f16 [64][256]  Mt[d][s]
constexpr int W_WEKH = 98304;    // f16 [64][64]   WekT[k][d]
constexpr int W_WEQH = 106496;   // f16 [64][64]   WeqT[k][d]
constexpr int W_BEQ  = 114688;   // f32[64]
constexpr int W_BEV  = 114944;   // f32[256]
constexpr int W_CS   = 115968;   // f32[256]
constexpr int W_CB   = 116992;   // f32[256]
constexpr int W_MS   = 118016;   // f32[64]
constexpr int W_C0   = 118272;   // f32[1]

// R10's proven high-parallelism pre kernels (99 + 66 blocks). R11's fused 33-block
// version was 60us: too few blocks to hide the serial load->use chains.
__global__ void pre1_kernel(const float* __restrict__ W_emb, const float* __restrict__ b_emb,
                            const float* __restrict__ W_k,   const float* __restrict__ W_q,
                            const float* __restrict__ b_q,   const float* __restrict__ W_v,
                            const float* __restrict__ b_v,   const float* __restrict__ W_d,
                            char* __restrict__ wsb) {
  int i = blockIdx.x * blockDim.x + threadIdx.x;
  if (i < 16384) {                       // Wev[d][h]
    int d = i >> 8, h = i & 255;
    float a = 0.f;
#pragma unroll 8
    for (int hp = 0; hp < 256; ++hp) a += W_emb[d*256 + hp] * W_v[hp*256 + h];
    ((float*)(wsb + W_WEV))[i] = a;
  } else if (i < 20480) {                // WekT[k][d]
    int j = i - 16384; int k = j & 63, d = j >> 6;
    float a = 0.f;
#pragma unroll 8
    for (int h = 0; h < 256; ++h) a += W_emb[d*256 + h] * W_k[h*64 + k];
    ((_Float16*)(wsb + W_WEKH))[k*64 + d] = (_Float16)a;
  } else if (i < 24576) {                // WeqT[k][d]
    int j = i - 20480; int k = j & 63, d = j >> 6;
    float a = 0.f;
#pragma unroll 8
    for (int h = 0; h < 256; ++h) a += W_emb[d*256 + h] * W_q[h*64 + k];
    ((_Float16*)(wsb + W_WEQH))[k*64 + d] = (_Float16)a;
  } else if (i < 24640) {                // beq[k]
    int k = i - 24576;
    float a = b_q[k];
    for (int h = 0; h < 256; ++h) a += b_emb[h] * W_q[h*64 + k];
    ((float*)(wsb + W_BEQ))[k] = a;
  } else if (i < 24896) {                // bev[h]
    int h = i - 24640;
    float a = b_v[h];
    for (int hp = 0; hp < 256; ++hp) a += b_emb[hp] * W_v[hp*256 + h];
    ((float*)(wsb + W_BEV))[h] = a;
  } else if (i < 25152) {                // cs[h]
    int h = i - 24896;
    float a = 0.f;
    for (int s = 0; s < 256; ++s) a += W_d[s*256 + h];
    ((float*)(wsb + W_CS))[h] = a;
  }
}

__global__ void pre2_kernel(const float* __restrict__ W_d, const float* __restrict__ b_d,
                            char* __restrict__ wsb) {
  int i = blockIdx.x * blockDim.x + threadIdx.x;
  const float* wev = (const float*)(wsb + W_WEV);
  if (i < 16384) {                       // Mt[d][s] = sum_h W_d[s,h]*Wev[d,h]
    int d = i >> 8, s = i & 255;
    float a = 0.f;
#pragma unroll 8
    for (int h = 0; h < 256; ++h) a += W_d[s*256 + h] * wev[d*256 + h];
    ((_Float16*)(wsb + W_MTH))[i] = (_Float16)a;
  } else if (i < 16640) {                // cb[s]
    int s = i - 16384;
    const float* bev = (const float*)(wsb + W_BEV);
    float a = 0.f;
    for (int h = 0; h < 256; ++h) a += W_d[s*256 + h] * bev[h];
    ((float*)(wsb + W_CB))[s] = a;
  } else if (i < 16704) {                // ms[d]
    int d = i - 16640;
    const float* cs = (const float*)(wsb + W_CS);
    float a = 0.f;
    for (int h = 0; h < 256; ++h) a += wev[d*256 + h] * cs[h];
    ((float*)(wsb + W_MS))[d] = a;
  } else if (i == 16704) {               // c0
    const float* cs  = (const float*)(wsb + W_CS);
    const float* bev = (const float*)(wsb + W_BEV);
    const float* beq = (const float*)(wsb + W_BEQ);
    float cbsum = 0.f;
    for (int h = 0; h < 256; ++h) cbsum += cs[h] * bev[h];
    float bqsum = 0.f;
    for (int k = 0; k < 64; ++k) bqsum += beq[k];
    ((float*)(wsb + W_C0))[0] = b_d[0] + cbsum * bqsum;
  }
}

// LDS byte-address helpers (G4 XOR swizzle)
__device__ __forceinline__ int adrR(int r, int c) {   // QT [64][256] f16 at 0, rows 512B
  return (((r << 9) + (c << 1)) ^ ((r & 7) << 4));
}
__device__ __forceinline__ int adrU(int k, int d) {   // U  [64][64]  f16 at 32768, rows 128B
  return 32768 + (((k << 7) + (d << 1)) ^ ((k & 7) << 4));
}

#define MFMA16(A, B, C) __builtin_amdgcn_mfma_f32_16x16x32_f16((A), (B), (C), 0, 0, 0)

__device__ __forceinline__ half8 cvt8v(float4 v0, float4 v1) {
  half8 h;
  h[0] = (_Float16)v0.x; h[1] = (_Float16)v0.y; h[2] = (_Float16)v0.z; h[3] = (_Float16)v0.w;
  h[4] = (_Float16)v1.x; h[5] = (_Float16)v1.y; h[6] = (_Float16)v1.z; h[7] = (_Float16)v1.w;
  return h;
}

// 512 blocks, 8 waves each, block handles batches (b, b+512). ALL input loads for both
// batches issued in one opening burst (512B/thread in flight) -> dense HBM stream; the
// latency-bound compute then runs on register-resident fragments.
// LDS: QT 32K | U 8K | scr floats at 40960. (512,4): proven spill-free budget.
__global__ __launch_bounds__(TS, 4) void main_kernel(const float* __restrict__ inp_g,
                                                     const char* __restrict__ wsb,
                                                     float* __restrict__ out) {
  __shared__ __align__(16) char smem[43136];
  float* scrf = (float*)(smem + 40960);

  const int b = blockIdx.x, t = threadIdx.x;
  const int l = t & 63, w = t >> 6;            // w = 0..7
  const int lhi = l >> 4, llo = l & 15;

  // ---- opening burst: 16 dwordx4 loads (both batches), then convert ----
  half8 Af0[4], Af1[4];
  {
    const float* inp0 = inp_g + (size_t)b * 16384;
    const float* inp1 = inp0 + (size_t)512 * 16384;
    const int srA = w * 32 + llo;
    float4 r0[8], r1[8];
#pragma unroll
    for (int tl = 0; tl < 2; ++tl)
#pragma unroll
      for (int ks = 0; ks < 2; ++ks) {
        const float* p0 = inp0 + (srA + tl * 16) * 64 + ks * 32 + lhi * 8;
        const float* p1 = inp1 + (srA + tl * 16) * 64 + ks * 32 + lhi * 8;
        r0[(tl*2+ks)*2]     = *(const float4*)p0;
        r0[(tl*2+ks)*2 + 1] = *(const float4*)(p0 + 4);
        r1[(tl*2+ks)*2]     = *(const float4*)p1;
        r1[(tl*2+ks)*2 + 1] = *(const float4*)(p1 + 4);
      }
#pragma unroll
    for (int j = 0; j < 4; ++j) {
      Af0[j] = cvt8v(r0[2*j], r0[2*j + 1]);
      Af1[j] = cvt8v(r1[2*j], r1[2*j + 1]);
    }
  }

  const f32x4 zero4 = {0.f, 0.f, 0.f, 0.f};

  auto process = [&](const half8 (&Af)[4], float* outp) {
    float acc = 0.f;
    half2v ep[2][4][2];   // packed exp(logits)

    // ---- Pass 1: logits = inp @ Wek; exp (no max: bias cancels); colsum partials ----
    {
      f32x4 clg[2][4];
#pragma unroll
      for (int tl = 0; tl < 2; ++tl)
#pragma unroll
        for (int n = 0; n < 4; ++n) clg[tl][n] = zero4;
      const _Float16* wekh = (const _Float16*)(wsb + W_WEKH);
#pragma unroll
      for (int ks = 0; ks < 2; ++ks) {
        const int kd = ks * 32 + lhi * 8;
        half8 Bk[4];
#pragma unroll
        for (int n = 0; n < 4; ++n) Bk[n] = *(const half8*)(wekh + (n * 16 + llo) * 64 + kd);
#pragma unroll
        for (int n = 0; n < 4; ++n) {
          clg[0][n] = MFMA16(Af[ks],     Bk[n], clg[0][n]);
          clg[1][n] = MFMA16(Af[2 + ks], Bk[n], clg[1][n]);
        }
      }
#pragma unroll
      for (int n = 0; n < 4; ++n) {
        float sum = 0.f;
        float ev[2][4];
#pragma unroll
        for (int tl = 0; tl < 2; ++tl)
#pragma unroll
          for (int r = 0; r < 4; ++r) { ev[tl][r] = __expf(clg[tl][n][r]); sum += ev[tl][r]; }
#pragma unroll
        for (int tl = 0; tl < 2; ++tl) {
          half2v p0, p1;
          p0[0] = (_Float16)ev[tl][0]; p0[1] = (_Float16)ev[tl][1];
          p1[0] = (_Float16)ev[tl][2]; p1[1] = (_Float16)ev[tl][3];
          ep[tl][n][0] = p0; ep[tl][n][1] = p1;
        }
        sum += __shfl_xor(sum, 16);
        sum += __shfl_xor(sum, 32);
        if (lhi == 0) scrf[(n * 16 + llo) * 8 + w] = sum;
      }
    }

    // ---- Pass 2: Q = inp @ Weq -> QT (f16, LDS) + cb-term ----
    {
      f32x4 cq[2][4];
#pragma unroll
      for (int tl = 0; tl < 2; ++tl)
#pragma unroll
        for (int n = 0; n < 4; ++n) cq[tl][n] = zero4;
      const _Float16* weqh = (const _Float16*)(wsb + W_WEQH);
#pragma unroll
      for (int ks = 0; ks < 2; ++ks) {
        const int kd = ks * 32 + lhi * 8;
        half8 Bq[4];
#pragma unroll
        for (int n = 0; n < 4; ++n) Bq[n] = *(const half8*)(weqh + (n * 16 + llo) * 64 + kd);
#pragma unroll
        for (int n = 0; n < 4; ++n) {
          cq[0][n] = MFMA16(Af[ks],     Bq[n], cq[0][n]);
          cq[1][n] = MFMA16(Af[2 + ks], Bq[n], cq[1][n]);
        }
      }
#pragma unroll
      for (int tl = 0; tl < 2; ++tl) {
        int sbase = w * 32 + tl * 16 + lhi * 4;
#pragma unroll
        for (int n = 0; n < 4; ++n) {
          half4 qh;
#pragma unroll
          for (int r = 0; r < 4; ++r) qh[r] = (_Float16)cq[tl][n][r];
          *(half4*)(smem + adrR(n * 16 + llo, sbase)) = qh;
        }
      }
      const float* cb = (const float*)(wsb + W_CB);
#pragma unroll
      for (int tl = 0; tl < 2; ++tl)
#pragma unroll
        for (int r = 0; r < 4; ++r) {
          float qs = (cq[tl][0][r] + cq[tl][1][r]) + (cq[tl][2][r] + cq[tl][3][r]);
          acc += cb[w * 32 + tl * 16 + lhi * 4 + r] * qs;
        }
    }
    __syncthreads();   // bar 1: QT + colsum partials visible

    // ---- Phase D: T = QT x Mt (K=256), Mt inline (L2-hot); U -> LDS f16 ----
    const int d0 = (w & 3) * 16;
    const int ka = (w >> 2) * 16, kb = ka + 32;
    {
      const _Float16* mth = (const _Float16*)(wsb + W_MTH);
      f32x4 cta = zero4, ctb = zero4;
#pragma unroll
      for (int ks = 0; ks < 8; ++ks) {
        const int kd = ks * 32 + lhi * 8;
        half8 Bm  = *(const half8*)(mth + (d0 + llo) * 256 + kd);
        half8 Aqa = *(const half8*)(smem + adrR(ka + llo, kd));
        half8 Aqb = *(const half8*)(smem + adrR(kb + llo, kd));
        cta = MFMA16(Aqa, Bm, cta);
        ctb = MFMA16(Aqb, Bm, ctb);
      }
      const float* beq = (const float*)(wsb + W_BEQ);
      const float* msv = (const float*)(wsb + W_MS);
      float msd = msv[d0 + llo];
#pragma unroll
      for (int r = 0; r < 4; ++r) {
        float Uva = cta[r] + beq[ka + lhi * 4 + r] * msd;
        *(_Float16*)(smem + adrU(ka + lhi * 4 + r, d0 + llo)) = (_Float16)Uva;
        float Uvb = ctb[r] + beq[kb + lhi * 4 + r] * msd;
        *(_Float16*)(smem + adrU(kb + lhi * 4 + r, d0 + llo)) = (_Float16)Uvb;
      }
    }
    __syncthreads();   // bar 2: U visible

    // ---- Phase E: G = inp @ U^T (reuses Af); acc += sum e*cg / colsum ----
    {
      f32x4 cga[4], cgb[4];
#pragma unroll
      for (int n = 0; n < 4; ++n) { cga[n] = zero4; cgb[n] = zero4; }
#pragma unroll
      for (int ks = 0; ks < 2; ++ks) {
        const int kd = ks * 32 + lhi * 8;
        half8 Bu[4];
#pragma unroll
        for (int n = 0; n < 4; ++n) Bu[n] = *(const half8*)(smem + adrU(n * 16 + llo, kd));
#pragma unroll
        for (int n = 0; n < 4; ++n) {
          cga[n] = MFMA16(Af[ks],     Bu[n], cga[n]);
          cgb[n] = MFMA16(Af[2 + ks], Bu[n], cgb[n]);
        }
      }
#pragma unroll
      for (int n = 0; n < 4; ++n) {
        const float4* cp = (const float4*)(scrf + (n * 16 + llo) * 8);
        float4 c0v = cp[0], c1v = cp[1];
        float ss = ((c0v.x + c0v.y) + (c0v.z + c0v.w)) + ((c1v.x + c1v.y) + (c1v.z + c1v.w));
        float rs = __builtin_amdgcn_rcpf(ss);
        float dot = 0.f;
#pragma unroll
        for (int r = 0; r < 4; ++r) {
          float ea = (float)ep[0][n][r >> 1][r & 1];
          float eb = (float)ep[1][n][r >> 1][r & 1];
          dot += ea * cga[n][r] + eb * cgb[n][r];
        }
        acc += dot * rs;
      }
    }

    // ---- block reduction ----
#pragma unroll
    for (int off = 32; off; off >>= 1) acc += __shfl_down(acc, off);
    if (l == 0) scrf[512 + w] = acc;
    __syncthreads();   // bar 3
    if (t == 0) {
      float tot = ((const float*)(wsb + W_C0))[0];
#pragma unroll
      for (int g = 0; g < 8; ++g) tot += scrf[512 + g];
      *outp = tot;
    }
  };

  process(Af0, out + b);
  process(Af1, out + b + 512);
}

extern "C" void kernel_launch(void* const* d_in, const int* in_sizes, int n_in,
                              void* d_out, int out_size, void* d_ws, size_t ws_size,
                              hipStream_t stream) {
  (void)in_sizes; (void)n_in; (void)out_size; (void)ws_size;
  const float* input_seq = (const float*)d_in[0];
  const float* W_emb = (const float*)d_in[1];
  const float* b_emb = (const float*)d_in[2];
  const float* W_k   = (const float*)d_in[3];
  const float* W_q   = (const float*)d_in[5];
  const float* b_q   = (const float*)d_in[6];
  const float* W_v   = (const float*)d_in[7];
  const float* b_v   = (const float*)d_in[8];
  const float* W_d   = (const float*)d_in[9];
  const float* b_d   = (const float*)d_in[10];
  char* wsb  = (char*)d_ws;
  float* out = (float*)d_out;

  pre1_kernel<<<(25152 + 255) / 256, 256, 0, stream>>>(
      W_emb, b_emb, W_k, W_q, b_q, W_v, b_v, W_d, wsb);
  pre2_kernel<<<(16705 + 255) / 256, 256, 0, stream>>>(W_d, b_d, wsb);
  main_kernel<<<512, TS, 0, stream>>>(input_seq, wsb, out);
}

// Round 14
// 62.581 us; speedup vs baseline: 1.4830x; 1.2954x over previous
//
#include <hip/hip_runtime.h>
#include <hip/hip_bf16.h>

typedef _Float16 half8 __attribute__((ext_vector_type(8)));
typedef _Float16 half4 __attribute__((ext_vector_type(4)));
typedef _Float16 half2v __attribute__((ext_vector_type(2)));
typedef float    f32x4 __attribute__((ext_vector_type(4)));

constexpr int Bb = 1024;
constexpr int TS = 512;   // 8 waves, 2 M-tiles per wave, ONE batch per block

// ---- workspace byte offsets (R10 layout) ----
constexpr int W_WEV  = 0;        // f32 [64][256]  Wev[d][h]   (pre1 -> pre2 only)
constexpr int W_MTH  = 65536;    // f16 [64][256]  Mt[d][s]
constexpr int W_WEKH = 98304;    // f16 [64][64]   WekT[k][d]
constexpr int W_WEQH = 106496;   // f16 [64][64]   WeqT[k][d]
constexpr int W_BEQ  = 114688;   // f32[64]
constexpr int W_BEV  = 114944;   // f32[256]
constexpr int W_CS   = 115968;   // f32[256]
constexpr int W_CB   = 116992;   // f32[256]
constexpr int W_MS   = 118016;   // f32[64]
constexpr int W_C0   = 118272;   // f32[1]

__global__ void pre1_kernel(const float* __restrict__ W_emb, const float* __restrict__ b_emb,
                            const float* __restrict__ W_k,   const float* __restrict__ W_q,
                            const float* __restrict__ b_q,   const float* __restrict__ W_v,
                            const float* __restrict__ b_v,   const float* __restrict__ W_d,
                            char* __restrict__ wsb) {
  int i = blockIdx.x * blockDim.x + threadIdx.x;
  if (i < 16384) {                       // Wev[d][h]
    int d = i >> 8, h = i & 255;
    float a = 0.f;
#pragma unroll 8
    for (int hp = 0; hp < 256; ++hp) a += W_emb[d*256 + hp] * W_v[hp*256 + h];
    ((float*)(wsb + W_WEV))[i] = a;
  } else if (i < 20480) {                // WekT[k][d]
    int j = i - 16384; int k = j & 63, d = j >> 6;
    float a = 0.f;
#pragma unroll 8
    for (int h = 0; h < 256; ++h) a += W_emb[d*256 + h] * W_k[h*64 + k];
    ((_Float16*)(wsb + W_WEKH))[k*64 + d] = (_Float16)a;
  } else if (i < 24576) {                // WeqT[k][d]
    int j = i - 20480; int k = j & 63, d = j >> 6;
    float a = 0.f;
#pragma unroll 8
    for (int h = 0; h < 256; ++h) a += W_emb[d*256 + h] * W_q[h*64 + k];
    ((_Float16*)(wsb + W_WEQH))[k*64 + d] = (_Float16)a;
  } else if (i < 24640) {                // beq[k]
    int k = i - 24576;
    float a = b_q[k];
    for (int h = 0; h < 256; ++h) a += b_emb[h] * W_q[h*64 + k];
    ((float*)(wsb + W_BEQ))[k] = a;
  } else if (i < 24896) {                // bev[h]
    int h = i - 24640;
    float a = b_v[h];
    for (int hp = 0; hp < 256; ++hp) a += b_emb[hp] * W_v[hp*256 + h];
    ((float*)(wsb + W_BEV))[h] = a;
  } else if (i < 25152) {                // cs[h]
    int h = i - 24896;
    float a = 0.f;
    for (int s = 0; s < 256; ++s) a += W_d[s*256 + h];
    ((float*)(wsb + W_CS))[h] = a;
  }
}

__global__ void pre2_kernel(const float* __restrict__ W_d, const float* __restrict__ b_d,
                            char* __restrict__ wsb) {
  int i = blockIdx.x * blockDim.x + threadIdx.x;
  const float* wev = (const float*)(wsb + W_WEV);
  if (i < 16384) {                       // Mt[d][s] = sum_h W_d[s,h]*Wev[d,h]
    int d = i >> 8, s = i & 255;
    float a = 0.f;
#pragma unroll 8
    for (int h = 0; h < 256; ++h) a += W_d[s*256 + h] * wev[d*256 + h];
    ((_Float16*)(wsb + W_MTH))[i] = (_Float16)a;
  } else if (i < 16640) {                // cb[s]
    int s = i - 16384;
    const float* bev = (const float*)(wsb + W_BEV);
    float a = 0.f;
    for (int h = 0; h < 256; ++h) a += W_d[s*256 + h] * bev[h];
    ((float*)(wsb + W_CB))[s] = a;
  } else if (i < 16704) {                // ms[d]
    int d = i - 16640;
    const float* cs = (const float*)(wsb + W_CS);
    float a = 0.f;
    for (int h = 0; h < 256; ++h) a += wev[d*256 + h] * cs[h];
    ((float*)(wsb + W_MS))[d] = a;
  } else if (i == 16704) {               // c0
    const float* cs  = (const float*)(wsb + W_CS);
    const float* bev = (const float*)(wsb + W_BEV);
    const float* beq = (const float*)(wsb + W_BEQ);
    float cbsum = 0.f;
    for (int h = 0; h < 256; ++h) cbsum += cs[h] * bev[h];
    float bqsum = 0.f;
    for (int k = 0; k < 64; ++k) bqsum += beq[k];
    ((float*)(wsb + W_C0))[0] = b_d[0] + cbsum * bqsum;
  }
}

// LDS byte-address helpers (G4 XOR swizzle)
__device__ __forceinline__ int adrR(int r, int c) {   // QT [64][256] f16 at 0, rows 512B
  return (((r << 9) + (c << 1)) ^ ((r & 7) << 4));
}
__device__ __forceinline__ int adrU(int k, int d) {   // U  [64][64]  f16 at 32768, rows 128B
  return 32768 + (((k << 7) + (d << 1)) ^ ((k & 7) << 4));
}

#define MFMA16(A, B, C) __builtin_amdgcn_mfma_f32_16x16x32_f16((A), (B), (C), 0, 0, 0)

__device__ __forceinline__ half8 cvt8v(float4 v0, float4 v1) {
  half8 h;
  h[0] = (_Float16)v0.x; h[1] = (_Float16)v0.y; h[2] = (_Float16)v0.z; h[3] = (_Float16)v0.w;
  h[4] = (_Float16)v1.x; h[5] = (_Float16)v1.y; h[6] = (_Float16)v1.z; h[7] = (_Float16)v1.w;
  return h;
}

// One block per batch (grid 1024), 8 waves, wave w owns s-rows 32w..32w+31.
// R14 change vs R10: Af staging split into (raw 8-load burst) then (convert) so all 8
// global loads are in flight simultaneously (R10 interleaved cvt -> ~2 outstanding).
// Raw burst = 32 VGPR, peak live ~87 -> fits the (512,4)=128 budget (no R13-style spill).
// LDS: QT 32K | U 8K | scr floats at 40960.
__global__ __launch_bounds__(TS, 4) void main_kernel(const float* __restrict__ inp_g,
                                                     const char* __restrict__ wsb,
                                                     float* __restrict__ out) {
  __shared__ __align__(16) char smem[43136];
  float* scrf = (float*)(smem + 40960);

  const int b = blockIdx.x, t = threadIdx.x;
  const int l = t & 63, w = t >> 6;            // w = 0..7
  const int lhi = l >> 4, llo = l & 15;

  // ---- opening burst: 8 raw float4 loads (all in flight), then convert ----
  half8 Af[4];
  {
    const float* inp = inp_g + (size_t)b * 16384;
    const int srA = w * 32 + llo;
    float4 r[8];
#pragma unroll
    for (int tl = 0; tl < 2; ++tl)
#pragma unroll
      for (int ks = 0; ks < 2; ++ks) {
        const float* p = inp + (srA + tl * 16) * 64 + ks * 32 + lhi * 8;
        r[(tl*2+ks)*2]     = *(const float4*)p;
        r[(tl*2+ks)*2 + 1] = *(const float4*)(p + 4);
      }
#pragma unroll
    for (int j = 0; j < 4; ++j) Af[j] = cvt8v(r[2*j], r[2*j + 1]);
  }

  const f32x4 zero4 = {0.f, 0.f, 0.f, 0.f};
  float acc = 0.f;
  half2v ep[2][4][2];   // packed exp(logits)

  // ---- Pass 1: logits = inp @ Wek; exp (no max: bias cancels); colsum partials ----
  {
    f32x4 clg[2][4];
#pragma unroll
    for (int tl = 0; tl < 2; ++tl)
#pragma unroll
      for (int n = 0; n < 4; ++n) clg[tl][n] = zero4;
    const _Float16* wekh = (const _Float16*)(wsb + W_WEKH);
#pragma unroll
    for (int ks = 0; ks < 2; ++ks) {
      const int kd = ks * 32 + lhi * 8;
      half8 Bk[4];
#pragma unroll
      for (int n = 0; n < 4; ++n) Bk[n] = *(const half8*)(wekh + (n * 16 + llo) * 64 + kd);
#pragma unroll
      for (int n = 0; n < 4; ++n) {
        clg[0][n] = MFMA16(Af[ks],     Bk[n], clg[0][n]);
        clg[1][n] = MFMA16(Af[2 + ks], Bk[n], clg[1][n]);
      }
    }
#pragma unroll
    for (int n = 0; n < 4; ++n) {
      float sum = 0.f;
      float ev[2][4];
#pragma unroll
      for (int tl = 0; tl < 2; ++tl)
#pragma unroll
        for (int r = 0; r < 4; ++r) { ev[tl][r] = __expf(clg[tl][n][r]); sum += ev[tl][r]; }
#pragma unroll
      for (int tl = 0; tl < 2; ++tl) {
        half2v p0, p1;
        p0[0] = (_Float16)ev[tl][0]; p0[1] = (_Float16)ev[tl][1];
        p1[0] = (_Float16)ev[tl][2]; p1[1] = (_Float16)ev[tl][3];
        ep[tl][n][0] = p0; ep[tl][n][1] = p1;
      }
      sum += __shfl_xor(sum, 16);
      sum += __shfl_xor(sum, 32);
      if (lhi == 0) scrf[(n * 16 + llo) * 8 + w] = sum;
    }
  }

  // ---- Pass 2: Q = inp @ Weq -> QT (f16, LDS) + cb-term (kills cq) ----
  {
    f32x4 cq[2][4];
#pragma unroll
    for (int tl = 0; tl < 2; ++tl)
#pragma unroll
      for (int n = 0; n < 4; ++n) cq[tl][n] = zero4;
    const _Float16* weqh = (const _Float16*)(wsb + W_WEQH);
#pragma unroll
    for (int ks = 0; ks < 2; ++ks) {
      const int kd = ks * 32 + lhi * 8;
      half8 Bq[4];
#pragma unroll
      for (int n = 0; n < 4; ++n) Bq[n] = *(const half8*)(weqh + (n * 16 + llo) * 64 + kd);
#pragma unroll
      for (int n = 0; n < 4; ++n) {
        cq[0][n] = MFMA16(Af[ks],     Bq[n], cq[0][n]);
        cq[1][n] = MFMA16(Af[2 + ks], Bq[n], cq[1][n]);
      }
    }
#pragma unroll
    for (int tl = 0; tl < 2; ++tl) {
      int sbase = w * 32 + tl * 16 + lhi * 4;
#pragma unroll
      for (int n = 0; n < 4; ++n) {
        half4 qh;
#pragma unroll
        for (int r = 0; r < 4; ++r) qh[r] = (_Float16)cq[tl][n][r];
        *(half4*)(smem + adrR(n * 16 + llo, sbase)) = qh;
      }
    }
    const float* cb = (const float*)(wsb + W_CB);
#pragma unroll
    for (int tl = 0; tl < 2; ++tl)
#pragma unroll
      for (int r = 0; r < 4; ++r) {
        float qs = (cq[tl][0][r] + cq[tl][1][r]) + (cq[tl][2][r] + cq[tl][3][r]);
        acc += cb[w * 32 + tl * 16 + lhi * 4 + r] * qs;
      }
  }
  __syncthreads();   // bar 1: QT + colsum partials visible

  // ---- Phase D: T = QT x Mt (K=256), Mt inline (L2-hot); U -> LDS f16 ----
  const int d0 = (w & 3) * 16;
  const int ka = (w >> 2) * 16, kb = ka + 32;
  {
    const _Float16* mth = (const _Float16*)(wsb + W_MTH);
    f32x4 cta = zero4, ctb = zero4;
#pragma unroll
    for (int ks = 0; ks < 8; ++ks) {
      const int kd = ks * 32 + lhi * 8;
      half8 Bm  = *(const half8*)(mth + (d0 + llo) * 256 + kd);
      half8 Aqa = *(const half8*)(smem + adrR(ka + llo, kd));
      half8 Aqb = *(const half8*)(smem + adrR(kb + llo, kd));
      cta = MFMA16(Aqa, Bm, cta);
      ctb = MFMA16(Aqb, Bm, ctb);
    }
    const float* beq = (const float*)(wsb + W_BEQ);
    const float* msv = (const float*)(wsb + W_MS);
    float msd = msv[d0 + llo];
#pragma unroll
    for (int r = 0; r < 4; ++r) {
      float Uva = cta[r] + beq[ka + lhi * 4 + r] * msd;
      *(_Float16*)(smem + adrU(ka + lhi * 4 + r, d0 + llo)) = (_Float16)Uva;
      float Uvb = ctb[r] + beq[kb + lhi * 4 + r] * msd;
      *(_Float16*)(smem + adrU(kb + lhi * 4 + r, d0 + llo)) = (_Float16)Uvb;
    }
  }
  __syncthreads();   // bar 2: U visible

  // ---- Phase E: G = inp @ U^T (reuses Af); acc += sum e*cg / colsum ----
  {
    f32x4 cga[4], cgb[4];
#pragma unroll
    for (int n = 0; n < 4; ++n) { cga[n] = zero4; cgb[n] = zero4; }
#pragma unroll
    for (int ks = 0; ks < 2; ++ks) {
      const int kd = ks * 32 + lhi * 8;
      half8 Bu[4];
#pragma unroll
      for (int n = 0; n < 4; ++n) Bu[n] = *(const half8*)(smem + adrU(n * 16 + llo, kd));
#pragma unroll
      for (int n = 0; n < 4; ++n) {
        cga[n] = MFMA16(Af[ks],     Bu[n], cga[n]);
        cgb[n] = MFMA16(Af[2 + ks], Bu[n], cgb[n]);
      }
    }
#pragma unroll
    for (int n = 0; n < 4; ++n) {
      const float4* cp = (const float4*)(scrf + (n * 16 + llo) * 8);
      float4 c0v = cp[0], c1v = cp[1];
      float ss = ((c0v.x + c0v.y) + (c0v.z + c0v.w)) + ((c1v.x + c1v.y) + (c1v.z + c1v.w));
      float rs = __builtin_amdgcn_rcpf(ss);
      float dot = 0.f;
#pragma unroll
      for (int r = 0; r < 4; ++r) {
        float ea = (float)ep[0][n][r >> 1][r & 1];
        float eb = (float)ep[1][n][r >> 1][r & 1];
        dot += ea * cga[n][r] + eb * cgb[n][r];
      }
      acc += dot * rs;
    }
  }

  // ---- block reduction ----
#pragma unroll
  for (int off = 32; off; off >>= 1) acc += __shfl_down(acc, off);
  if (l == 0) scrf[512 + w] = acc;
  __syncthreads();   // bar 3
  if (t == 0) {
    float tot = ((const float*)(wsb + W_C0))[0];
#pragma unroll
    for (int g = 0; g < 8; ++g) tot += scrf[512 + g];
    out[b] = tot;
  }
}

extern "C" void kernel_launch(void* const* d_in, const int* in_sizes, int n_in,
                              void* d_out, int out_size, void* d_ws, size_t ws_size,
                              hipStream_t stream) {
  (void)in_sizes; (void)n_in; (void)out_size; (void)ws_size;
  const float* input_seq = (const float*)d_in[0];
  const float* W_emb = (const float*)d_in[1];
  const float* b_emb = (const float*)d_in[2];
  const float* W_k   = (const float*)d_in[3];
  const float* W_q   = (const float*)d_in[5];
  const float* b_q   = (const float*)d_in[6];
  const float* W_v   = (const float*)d_in[7];
  const float* b_v   = (const float*)d_in[8];
  const float* W_d   = (const float*)d_in[9];
  const float* b_d   = (const float*)d_in[10];
  char* wsb  = (char*)d_ws;
  float* out = (float*)d_out;

  pre1_kernel<<<(25152 + 255) / 256, 256, 0, stream>>>(
      W_emb, b_emb, W_k, W_q, b_q, W_v, b_v, W_d, wsb);
  pre2_kernel<<<(16705 + 255) / 256, 256, 0, stream>>>(W_d, b_d, wsb);
  main_kernel<<<Bb, TS, 0, stream>>>(input_seq, wsb, out);
}